// Round 8
// baseline (160.525 us; speedup 1.0000x reference)
//
#include <hip/hip_runtime.h>
#include <float.h>
#include <math.h>

// Problem constants (fixed by reference setup_inputs)
constexpr int NQ = 2048;    // queries
constexpr int ND = 65536;   // data points
constexpr int D  = 16;      // dims

// ---- MFMA-path tiling (R4 champion structure: 85.0 us, absmax 1.95e-3) ----
constexpr int SCH   = 64;           // point chunks (grid.y)
constexpr int CP    = ND / SCH;     // 1024 points per chunk
constexpr int TPW   = CP / 32;      // 32 point-tiles (32 pts) per wave
constexpr int NPAIR = TPW / 2;      // 16 tile-pairs
constexpr int QCOLS = NQ / 128;     // 16 query columns (grid.x)

typedef short bf16x8 __attribute__((ext_vector_type(8)));
typedef float f32x16 __attribute__((ext_vector_type(16)));

__device__ __forceinline__ unsigned short f2bf(float f) {  // RNE fp32->bf16
    unsigned u = __float_as_uint(f);
    u += 0x7FFFu + ((u >> 16) & 1u);
    return (unsigned short)(u >> 16);
}
__device__ __forceinline__ float bf2f(unsigned short h) {
    return __uint_as_float(((unsigned)h) << 16);
}

// ---------------------------------------------------------------------------
// Pack kernel: Ppk[ND][32] = [ph(16)|pl(16)] bf16, nhf[ND] = -0.5*||p||^2.
// Also zeroes the last-block counters (ws is poisoned 0xAA before every call).
// ---------------------------------------------------------------------------
__global__ __launch_bounds__(256) void pack_data(const float* __restrict__ data,
                                                 unsigned short* __restrict__ Ppk,
                                                 float* __restrict__ nhf,
                                                 int* __restrict__ cnt) {
    if (blockIdx.x == 0 && threadIdx.x < QCOLS) cnt[threadIdx.x] = 0;

    const int p = blockIdx.x * 256 + threadIdx.x;
    const float4* r4 = (const float4*)(data + (size_t)p * D);
    float4 a = r4[0], b = r4[1], c = r4[2], e = r4[3];
    float v[16] = {a.x, a.y, a.z, a.w, b.x, b.y, b.z, b.w,
                   c.x, c.y, c.z, c.w, e.x, e.y, e.z, e.w};
    unsigned short row[32];
    float n = 0.f;
#pragma unroll
    for (int k = 0; k < 16; ++k) {
        n = fmaf(v[k], v[k], n);
        unsigned short h = f2bf(v[k]);
        row[k]      = h;
        row[16 + k] = f2bf(v[k] - bf2f(h));   // exact residual, rounded to bf16
    }
    uint4* w4 = (uint4*)(Ppk + (size_t)p * 32);
    const uint4* rr = (const uint4*)row;
    w4[0] = rr[0]; w4[1] = rr[1]; w4[2] = rr[2]; w4[3] = rr[3];
    nhf[p] = -0.5f * n;
}

// ---------------------------------------------------------------------------
// Main kernel (champion body + fused final): per wave, 32 queries x one
// 1024-point chunk.  best[q] = max_p ( x.p - 0.5*||p||^2 ).
// 3x mfma_f32_32x32x16_bf16 per 32-pt tile (hh + lh + hl), C seeded with
// -0.5*||p||^2 (read from a 4-KB LDS stage, conflict-free [t*32+n31]).
// Tile PAIRS with ping-pong register prefetch; per-pair epilogue = v_max3.
// A-frag: lane holds x[qbase + (l&31)][ (l>>5)*8 + j ]  (HW-verified R3/R4).
// C/D: col = lane&31, row = (reg&3) + 8*(reg>>2) + 4*(lane>>5)  [m74/m101].
// After writing its part slice, the LAST block of each query column reduces
// all SCH partials and writes the bump output (threadfence + atomic counter).
// ---------------------------------------------------------------------------
__global__ __launch_bounds__(256, 4) void knn_mfma(const float* __restrict__ x,
                                                   const unsigned short* __restrict__ Ppk,
                                                   const float* __restrict__ nhf,
                                                   float* __restrict__ part,
                                                   int* __restrict__ cnt,
                                                   float* __restrict__ out) {
    __shared__ float snrm[CP];     // 4 KB: this chunk's -0.5*||p||^2
    __shared__ int   sdone;

    const int tid  = threadIdx.x;
    const int w    = tid >> 6;
    const int l    = tid & 63;
    const int half = l >> 5;
    const int n31  = l & 31;
    const int qbase = blockIdx.x * 128 + w * 32;   // 4 waves x 32 queries
    const int pbase = blockIdx.y * CP;

    // ---- Stage this chunk's norms into LDS (coalesced, 4 rounds) ----
#pragma unroll
    for (int i = 0; i < CP / 256; ++i)
        snrm[i * 256 + tid] = nhf[pbase + i * 256 + tid];

    // ---- Build A fragments (hi/lo bf16) from raw fp32 x ----
    bf16x8 axh, axl;
    {
        const float* xr = x + (size_t)(qbase + n31) * D + half * 8;
        float4 x0 = *(const float4*)xr;
        float4 x1 = *(const float4*)(xr + 4);
        const float xv[8] = {x0.x, x0.y, x0.z, x0.w, x1.x, x1.y, x1.z, x1.w};
#pragma unroll
        for (int k = 0; k < 8; ++k) {
            unsigned short h = f2bf(xv[k]);
            axh[k] = (short)h;
            axl[k] = (short)f2bf(xv[k] - bf2f(h));
        }
    }

    // B-side pointer (per-lane point column). Tile t: +t*1024 shorts.
    const unsigned short* bp = Ppk + (size_t)(pbase + n31) * 32 + half * 8;

#define LDH(t) (*(const bf16x8*)(bp + (size_t)(t) * 1024))
#define LDL(t) (*(const bf16x8*)(bp + (size_t)(t) * 1024 + 16))
#define LDN(t) (snrm[(t) * 32 + n31])

    f32x16 rbest;
#pragma unroll
    for (int r = 0; r < 16; ++r) rbest[r] = -FLT_MAX;

    auto compute_pair = [&](bf16x8 h0, bf16x8 l0, float n0,
                            bf16x8 h1, bf16x8 l1, float n1) {
        f32x16 c0, c1;
#pragma unroll
        for (int r = 0; r < 16; ++r) { c0[r] = n0; c1[r] = n1; }
        c0 = __builtin_amdgcn_mfma_f32_32x32x16_bf16(axh, h0, c0, 0, 0, 0);
        c1 = __builtin_amdgcn_mfma_f32_32x32x16_bf16(axh, h1, c1, 0, 0, 0);
        c0 = __builtin_amdgcn_mfma_f32_32x32x16_bf16(axl, h0, c0, 0, 0, 0);
        c1 = __builtin_amdgcn_mfma_f32_32x32x16_bf16(axl, h1, c1, 0, 0, 0);
        c0 = __builtin_amdgcn_mfma_f32_32x32x16_bf16(axh, l0, c0, 0, 0, 0);
        c1 = __builtin_amdgcn_mfma_f32_32x32x16_bf16(axh, l1, c1, 0, 0, 0);
#pragma unroll
        for (int r = 0; r < 16; ++r)
            rbest[r] = fmaxf(rbest[r], fmaxf(c0[r], c1[r]));  // -> v_max3_f32
    };

    // B hi/lo initial loads (global; independent of LDS stage)
    bf16x8 Ah0 = LDH(0), Al0 = LDL(0), Ah1 = LDH(1), Al1 = LDL(1);
    bf16x8 Bh0, Bl0, Bh1, Bl1;

    __syncthreads();   // norms staged

    float An0 = LDN(0), An1 = LDN(1);
    float Bn0, Bn1;

    for (int p = 0; p < NPAIR; p += 2) {
        const int tB = (p + 1) * 2;
        Bh0 = LDH(tB);     Bl0 = LDL(tB);     Bn0 = LDN(tB);
        Bh1 = LDH(tB + 1); Bl1 = LDL(tB + 1); Bn1 = LDN(tB + 1);
        compute_pair(Ah0, Al0, An0, Ah1, Al1, An1);
        if (p + 2 < NPAIR) {
            const int tA = (p + 2) * 2;
            Ah0 = LDH(tA);     Al0 = LDL(tA);     An0 = LDN(tA);
            Ah1 = LDH(tA + 1); Al1 = LDL(tA + 1); An1 = LDN(tA + 1);
        }
        compute_pair(Bh0, Bl0, Bn0, Bh1, Bl1, Bn1);
    }
#undef LDH
#undef LDL
#undef LDN

    // max over the 32 point-columns (lanes within each half)
#pragma unroll
    for (int r = 0; r < 16; ++r) {
        float v = rbest[r];
#pragma unroll
        for (int m = 1; m < 32; m <<= 1) v = fmaxf(v, __shfl_xor(v, m, 32));
        rbest[r] = v;
    }
    if (n31 == 0) {
        float* pp = part + (size_t)blockIdx.y * NQ + qbase + 4 * half;
#pragma unroll
        for (int r = 0; r < 16; ++r) pp[(r & 3) + 8 * (r >> 2)] = rbest[r];
    }

    // ---- Last-block-done: the final arriving block of this query column
    //      reduces all SCH partials and writes the bump output. ----
    __threadfence();      // make part stores visible device-wide
    __syncthreads();      // all waves' stores fenced
    if (tid == 0) {
        const int old = atomicAdd(&cnt[blockIdx.x], 1);
        sdone = (old == SCH - 1);
    }
    __syncthreads();
    if (sdone) {
        __threadfence();  // acquire: see all columns' part stores
        if (tid < 128) {
            const int q = blockIdx.x * 128 + tid;
            float m0 = -FLT_MAX, m1 = -FLT_MAX, m2 = -FLT_MAX, m3 = -FLT_MAX;
#pragma unroll
            for (int cI = 0; cI < SCH; cI += 4) {
                m0 = fmaxf(m0, part[(size_t)(cI + 0) * NQ + q]);
                m1 = fmaxf(m1, part[(size_t)(cI + 1) * NQ + q]);
                m2 = fmaxf(m2, part[(size_t)(cI + 2) * NQ + q]);
                m3 = fmaxf(m3, part[(size_t)(cI + 3) * NQ + q]);
            }
            const float mbest = fmaxf(fmaxf(m0, m1), fmaxf(m2, m3));

            const float4* xr = (const float4*)(x + (size_t)q * D);
            float4 a = xr[0], b = xr[1], c = xr[2], e = xr[3];
            float x2 = a.x * a.x;
            x2 = fmaf(a.y, a.y, x2); x2 = fmaf(a.z, a.z, x2); x2 = fmaf(a.w, a.w, x2);
            x2 = fmaf(b.x, b.x, x2); x2 = fmaf(b.y, b.y, x2); x2 = fmaf(b.z, b.z, x2); x2 = fmaf(b.w, b.w, x2);
            x2 = fmaf(c.x, c.x, x2); x2 = fmaf(c.y, c.y, x2); x2 = fmaf(c.z, c.z, x2); x2 = fmaf(c.w, c.w, x2);
            x2 = fmaf(e.x, e.x, x2); x2 = fmaf(e.y, e.y, x2); x2 = fmaf(e.z, e.z, x2); x2 = fmaf(e.w, e.w, x2);

            float nn2  = fmaxf(fmaf(-2.f, mbest, x2), 0.f);
            float dist = sqrtf(fmaxf(nn2, 1e-12f));
            float bump = 0.f;
            if (dist < 2.0f) {                      // RADIUS = 2
                float denom = dist * dist - 4.0f;   // d^2 - r^2
                bump = expf(1.0f / denom + 0.25f);  // DECAY/denom + DECAY/r^2
            }
            out[q] = bump;
        }
    }
}

// ===========================================================================
// Fallback (fp32 scalar-pipe path) if workspace is too small for MFMA path.
// ===========================================================================
__global__ __launch_bounds__(256) void neg_half_norms(const float* __restrict__ data,
                                                      float* __restrict__ nhn) {
    const int p = blockIdx.x * 256 + threadIdx.x;
    const float4* r = (const float4*)(data + (size_t)p * D);
    float4 a = r[0], b = r[1], c = r[2], e = r[3];
    float n = a.x * a.x;
    n = fmaf(a.y, a.y, n); n = fmaf(a.z, a.z, n); n = fmaf(a.w, a.w, n);
    n = fmaf(b.x, b.x, n); n = fmaf(b.y, b.y, n); n = fmaf(b.z, b.z, n); n = fmaf(b.w, b.w, n);
    n = fmaf(c.x, c.x, n); n = fmaf(c.y, c.y, n); n = fmaf(c.z, c.z, n); n = fmaf(c.w, c.w, n);
    n = fmaf(e.x, e.x, n); n = fmaf(e.y, e.y, n); n = fmaf(e.z, e.z, n); n = fmaf(e.w, e.w, n);
    nhn[p] = -0.5f * n;
}

__global__ __launch_bounds__(256) void knn_partial_fb(const float* __restrict__ x,
                                                      const float* __restrict__ data,
                                                      const float* __restrict__ nhn,
                                                      float* __restrict__ part, int cp) {
    const int q     = blockIdx.x * 256 + threadIdx.x;
    const int pbase = blockIdx.y * cp;
    const float4* xr = (const float4*)(x + (size_t)q * D);
    const float4 xa = xr[0], xb = xr[1], xc = xr[2], xd = xr[3];
    const float* dp = data + (size_t)pbase * D;
    const float* np = nhn + pbase;
    float best = -FLT_MAX;
    for (int i = 0; i < cp; i += 4) {
#pragma unroll
        for (int j = 0; j < 4; ++j) {
            const float* r  = dp + (size_t)(i + j) * D;
            const float  hn = np[i + j];
            float ca = xa.x * r[0];
            ca = fmaf(xa.y, r[1], ca);  ca = fmaf(xa.z, r[2], ca);  ca = fmaf(xa.w, r[3], ca);
            ca = fmaf(xb.x, r[4], ca);  ca = fmaf(xb.y, r[5], ca);  ca = fmaf(xb.z, r[6], ca);
            ca = fmaf(xb.w, r[7], ca);
            float cb = fmaf(xc.x, r[8], hn);
            cb = fmaf(xc.y, r[9],  cb); cb = fmaf(xc.z, r[10], cb); cb = fmaf(xc.w, r[11], cb);
            cb = fmaf(xd.x, r[12], cb); cb = fmaf(xd.y, r[13], cb); cb = fmaf(xd.z, r[14], cb);
            cb = fmaf(xd.w, r[15], cb);
            best = fmaxf(best, ca + cb);
        }
    }
    part[(size_t)blockIdx.y * NQ + q] = best;
}

__global__ __launch_bounds__(256) void knn_final_fb(const float* __restrict__ x,
                                                    const float* __restrict__ part,
                                                    float* __restrict__ out, int S) {
    const int q = blockIdx.x * 256 + threadIdx.x;
    const float4* xr = (const float4*)(x + (size_t)q * D);
    float4 a = xr[0], b = xr[1], c = xr[2], e = xr[3];
    float x2 = a.x * a.x;
    x2 = fmaf(a.y, a.y, x2); x2 = fmaf(a.z, a.z, x2); x2 = fmaf(a.w, a.w, x2);
    x2 = fmaf(b.x, b.x, x2); x2 = fmaf(b.y, b.y, x2); x2 = fmaf(b.z, b.z, x2); x2 = fmaf(b.w, b.w, x2);
    x2 = fmaf(c.x, c.x, x2); x2 = fmaf(c.y, c.y, x2); x2 = fmaf(c.z, c.z, x2); x2 = fmaf(c.w, c.w, x2);
    x2 = fmaf(e.x, e.x, x2); x2 = fmaf(e.y, e.y, x2); x2 = fmaf(e.z, e.z, x2); x2 = fmaf(e.w, e.w, x2);
    float mb = -FLT_MAX;
    for (int cI = 0; cI < S; ++cI) mb = fmaxf(mb, part[(size_t)cI * NQ + q]);
    float nn2  = fmaxf(fmaf(-2.f, mb, x2), 0.f);
    float dist = sqrtf(fmaxf(nn2, 1e-12f));
    float bump = 0.f;
    if (dist < 2.0f) {
        float denom = dist * dist - 4.0f;
        bump = expf(1.0f / denom + 0.25f);
    }
    out[q] = bump;
}

extern "C" void kernel_launch(void* const* d_in, const int* in_sizes, int n_in,
                              void* d_out, int out_size, void* d_ws, size_t ws_size,
                              hipStream_t stream) {
    const float* x    = (const float*)d_in[0];   // [2048,16] fp32
    const float* data = (const float*)d_in[1];   // [65536,16] fp32
    float* out = (float*)d_out;                  // [2048] fp32

    // ws layout (bytes):
    //   Ppk  [0, 4 MiB)          ND*32 bf16
    //   nhf  [4 MiB, +256 KiB)   ND fp32
    //   part [+256 KiB)          SCH*NQ fp32 (512 KiB)
    //   cnt  [+512 KiB)          QCOLS ints (last-block counters)
    const size_t off_nhf  = (size_t)ND * 32 * 2;             // 4194304
    const size_t off_part = off_nhf + (size_t)ND * 4;        // 4456448
    const size_t off_cnt  = off_part + (size_t)SCH * NQ * 4; // 4980736
    const size_t needed   = off_cnt + QCOLS * sizeof(int);

    if (ws_size >= needed) {
        unsigned short* Ppk = (unsigned short*)d_ws;
        float* nhf  = (float*)((char*)d_ws + off_nhf);
        float* part = (float*)((char*)d_ws + off_part);
        int*   cnt  = (int*)((char*)d_ws + off_cnt);

        pack_data<<<ND / 256, 256, 0, stream>>>(data, Ppk, nhf, cnt);
        knn_mfma<<<dim3(QCOLS, SCH), 256, 0, stream>>>(x, Ppk, nhf, part, cnt, out);
    } else {
        int S = 32;
        while (S > 1 && (size_t)(ND + S * NQ) * sizeof(float) > ws_size) S >>= 1;
        const int cp = ND / S;
        float* nhn  = (float*)d_ws;
        float* part = (float*)d_ws + ND;
        neg_half_norms<<<ND / 256, 256, 0, stream>>>(data, nhn);
        knn_partial_fb<<<dim3(NQ / 256, S), 256, 0, stream>>>(x, data, nhn, part, cp);
        knn_final_fb<<<NQ / 256, 256, 0, stream>>>(x, part, out, S);
    }
}

// Round 9
// 104.213 us; speedup vs baseline: 1.5403x; 1.5403x over previous
//
#include <hip/hip_runtime.h>
#include <float.h>
#include <math.h>

// Problem constants (fixed by reference setup_inputs)
constexpr int NQ = 2048;    // queries
constexpr int ND = 65536;   // data points
constexpr int D  = 16;      // dims

// ---- MFMA-path tiling ----
// grid = (SCH chunks on x, QCOLS qcols on y): chunk is the FAST dispatch dim,
// so the 16 blocks sharing a chunk are 128 apart linearly -> same XCD under
// round-robin, keeping each chunk L2-resident on one XCD (R8 showed 5x HBM
// over-fetch without this). SCH=128 -> 2048 blocks = 8 blocks/CU at VGPR=64.
constexpr int SCH   = 128;          // point chunks (grid.x)
constexpr int CP    = ND / SCH;     // 512 points per chunk
constexpr int TPW   = CP / 32;      // 16 point-tiles (32 pts) per wave
constexpr int NPAIR = TPW / 2;      // 8 tile-pairs
constexpr int QCOLS = NQ / 128;     // 16 query columns (grid.y)

typedef short bf16x8 __attribute__((ext_vector_type(8)));
typedef float f32x16 __attribute__((ext_vector_type(16)));

__device__ __forceinline__ unsigned short f2bf(float f) {  // RNE fp32->bf16
    unsigned u = __float_as_uint(f);
    u += 0x7FFFu + ((u >> 16) & 1u);
    return (unsigned short)(u >> 16);
}
__device__ __forceinline__ float bf2f(unsigned short h) {
    return __uint_as_float(((unsigned)h) << 16);
}

// ---------------------------------------------------------------------------
// Pack kernel: Ppk[ND][32] = [ph(16)|pl(16)] bf16, nhf[ND] = -0.5*||p||^2.
// ---------------------------------------------------------------------------
__global__ __launch_bounds__(256) void pack_data(const float* __restrict__ data,
                                                 unsigned short* __restrict__ Ppk,
                                                 float* __restrict__ nhf) {
    const int p = blockIdx.x * 256 + threadIdx.x;
    const float4* r4 = (const float4*)(data + (size_t)p * D);
    float4 a = r4[0], b = r4[1], c = r4[2], e = r4[3];
    float v[16] = {a.x, a.y, a.z, a.w, b.x, b.y, b.z, b.w,
                   c.x, c.y, c.z, c.w, e.x, e.y, e.z, e.w};
    unsigned short row[32];
    float n = 0.f;
#pragma unroll
    for (int k = 0; k < 16; ++k) {
        n = fmaf(v[k], v[k], n);
        unsigned short h = f2bf(v[k]);
        row[k]      = h;
        row[16 + k] = f2bf(v[k] - bf2f(h));   // exact residual, rounded to bf16
    }
    uint4* w4 = (uint4*)(Ppk + (size_t)p * 32);
    const uint4* rr = (const uint4*)row;
    w4[0] = rr[0]; w4[1] = rr[1]; w4[2] = rr[2]; w4[3] = rr[3];
    nhf[p] = -0.5f * n;
}

// ---------------------------------------------------------------------------
// Main kernel (champion body, unfused): per wave, 32 queries x one 512-point
// chunk.  best[q] = max_p ( x.p - 0.5*||p||^2 )  (argmin dist2 == argmax).
// 3x mfma_f32_32x32x16_bf16 per 32-pt tile (hh + lh + hl), C seeded with
// -0.5*||p||^2 read from a 2-KB LDS stage (conflict-free [t*32+n31]).
// Tile PAIRS with ping-pong register prefetch; per-pair epilogue = v_max3.
// A-frag: lane holds x[qbase + (l&31)][ (l>>5)*8 + j ]  (HW-verified R3/R4).
// C/D: col = lane&31, row = (reg&3) + 8*(reg>>2) + 4*(lane>>5)  [m74/m101].
// NO cross-block fences (R8: __threadfence per block caused L2 flush storms).
// ---------------------------------------------------------------------------
__global__ __launch_bounds__(256, 4) void knn_mfma(const float* __restrict__ x,
                                                   const unsigned short* __restrict__ Ppk,
                                                   const float* __restrict__ nhf,
                                                   float* __restrict__ part) {
    __shared__ float snrm[CP];     // 2 KB: this chunk's -0.5*||p||^2

    const int tid  = threadIdx.x;
    const int w    = tid >> 6;
    const int l    = tid & 63;
    const int half = l >> 5;
    const int n31  = l & 31;
    const int qbase = blockIdx.y * 128 + w * 32;   // 4 waves x 32 queries
    const int pbase = blockIdx.x * CP;             // chunk on FAST dim (XCD swizzle)

    // ---- Stage this chunk's norms into LDS (coalesced, 2 rounds) ----
#pragma unroll
    for (int i = 0; i < CP / 256; ++i)
        snrm[i * 256 + tid] = nhf[pbase + i * 256 + tid];

    // ---- Build A fragments (hi/lo bf16) from raw fp32 x ----
    bf16x8 axh, axl;
    {
        const float* xr = x + (size_t)(qbase + n31) * D + half * 8;
        float4 x0 = *(const float4*)xr;
        float4 x1 = *(const float4*)(xr + 4);
        const float xv[8] = {x0.x, x0.y, x0.z, x0.w, x1.x, x1.y, x1.z, x1.w};
#pragma unroll
        for (int k = 0; k < 8; ++k) {
            unsigned short h = f2bf(xv[k]);
            axh[k] = (short)h;
            axl[k] = (short)f2bf(xv[k] - bf2f(h));
        }
    }

    // B-side pointer (per-lane point column). Tile t: +t*1024 shorts.
    const unsigned short* bp = Ppk + (size_t)(pbase + n31) * 32 + half * 8;

#define LDH(t) (*(const bf16x8*)(bp + (size_t)(t) * 1024))
#define LDL(t) (*(const bf16x8*)(bp + (size_t)(t) * 1024 + 16))
#define LDN(t) (snrm[(t) * 32 + n31])

    f32x16 rbest;
#pragma unroll
    for (int r = 0; r < 16; ++r) rbest[r] = -FLT_MAX;

    auto compute_pair = [&](bf16x8 h0, bf16x8 l0, float n0,
                            bf16x8 h1, bf16x8 l1, float n1) {
        f32x16 c0, c1;
#pragma unroll
        for (int r = 0; r < 16; ++r) { c0[r] = n0; c1[r] = n1; }
        c0 = __builtin_amdgcn_mfma_f32_32x32x16_bf16(axh, h0, c0, 0, 0, 0);
        c1 = __builtin_amdgcn_mfma_f32_32x32x16_bf16(axh, h1, c1, 0, 0, 0);
        c0 = __builtin_amdgcn_mfma_f32_32x32x16_bf16(axl, h0, c0, 0, 0, 0);
        c1 = __builtin_amdgcn_mfma_f32_32x32x16_bf16(axl, h1, c1, 0, 0, 0);
        c0 = __builtin_amdgcn_mfma_f32_32x32x16_bf16(axh, l0, c0, 0, 0, 0);
        c1 = __builtin_amdgcn_mfma_f32_32x32x16_bf16(axh, l1, c1, 0, 0, 0);
#pragma unroll
        for (int r = 0; r < 16; ++r)
            rbest[r] = fmaxf(rbest[r], fmaxf(c0[r], c1[r]));  // -> v_max3_f32
    };

    // B hi/lo initial loads (global; independent of LDS stage)
    bf16x8 Ah0 = LDH(0), Al0 = LDL(0), Ah1 = LDH(1), Al1 = LDL(1);
    bf16x8 Bh0, Bl0, Bh1, Bl1;

    __syncthreads();   // norms staged

    float An0 = LDN(0), An1 = LDN(1);
    float Bn0, Bn1;

    for (int p = 0; p < NPAIR; p += 2) {
        const int tB = (p + 1) * 2;
        Bh0 = LDH(tB);     Bl0 = LDL(tB);     Bn0 = LDN(tB);
        Bh1 = LDH(tB + 1); Bl1 = LDL(tB + 1); Bn1 = LDN(tB + 1);
        compute_pair(Ah0, Al0, An0, Ah1, Al1, An1);
        if (p + 2 < NPAIR) {
            const int tA = (p + 2) * 2;
            Ah0 = LDH(tA);     Al0 = LDL(tA);     An0 = LDN(tA);
            Ah1 = LDH(tA + 1); Al1 = LDL(tA + 1); An1 = LDN(tA + 1);
        }
        compute_pair(Bh0, Bl0, Bn0, Bh1, Bl1, Bn1);
    }
#undef LDH
#undef LDL
#undef LDN

    // max over the 32 point-columns (lanes within each half)
#pragma unroll
    for (int r = 0; r < 16; ++r) {
        float v = rbest[r];
#pragma unroll
        for (int m = 1; m < 32; m <<= 1) v = fmaxf(v, __shfl_xor(v, m, 32));
        rbest[r] = v;
    }
    if (n31 == 0) {
        float* pp = part + (size_t)blockIdx.x * NQ + qbase + 4 * half;
#pragma unroll
        for (int r = 0; r < 16; ++r) pp[(r & 3) + 8 * (r >> 2)] = rbest[r];
    }
}

// ---------------------------------------------------------------------------
// Final: reduce SCH chunks, dist2 = ||x||^2 - 2*best, bump.
// Coalesced across q each chunk iteration; 4 independent accumulators.
// ---------------------------------------------------------------------------
__global__ __launch_bounds__(256) void knn_final(const float* __restrict__ x,
                                                 const float* __restrict__ part,
                                                 float* __restrict__ out) {
    const int q = blockIdx.x * 256 + threadIdx.x;
    const float4* xr = (const float4*)(x + (size_t)q * D);
    float4 a = xr[0], b = xr[1], c = xr[2], e = xr[3];
    float x2 = a.x * a.x;
    x2 = fmaf(a.y, a.y, x2); x2 = fmaf(a.z, a.z, x2); x2 = fmaf(a.w, a.w, x2);
    x2 = fmaf(b.x, b.x, x2); x2 = fmaf(b.y, b.y, x2); x2 = fmaf(b.z, b.z, x2); x2 = fmaf(b.w, b.w, x2);
    x2 = fmaf(c.x, c.x, x2); x2 = fmaf(c.y, c.y, x2); x2 = fmaf(c.z, c.z, x2); x2 = fmaf(c.w, c.w, x2);
    x2 = fmaf(e.x, e.x, x2); x2 = fmaf(e.y, e.y, x2); x2 = fmaf(e.z, e.z, x2); x2 = fmaf(e.w, e.w, x2);

    float m0 = -FLT_MAX, m1 = -FLT_MAX, m2 = -FLT_MAX, m3 = -FLT_MAX;
#pragma unroll
    for (int cI = 0; cI < SCH; cI += 4) {
        m0 = fmaxf(m0, part[(size_t)(cI + 0) * NQ + q]);
        m1 = fmaxf(m1, part[(size_t)(cI + 1) * NQ + q]);
        m2 = fmaxf(m2, part[(size_t)(cI + 2) * NQ + q]);
        m3 = fmaxf(m3, part[(size_t)(cI + 3) * NQ + q]);
    }
    float mbest = fmaxf(fmaxf(m0, m1), fmaxf(m2, m3));

    float nn2  = fmaxf(fmaf(-2.f, mbest, x2), 0.f);
    float dist = sqrtf(fmaxf(nn2, 1e-12f));
    float bump = 0.f;
    if (dist < 2.0f) {                      // RADIUS = 2
        float denom = dist * dist - 4.0f;   // d^2 - r^2
        bump = expf(1.0f / denom + 0.25f);  // DECAY/denom + DECAY/r^2
    }
    out[q] = bump;
}

// ===========================================================================
// Fallback (fp32 scalar-pipe path) if workspace is too small for MFMA path.
// ===========================================================================
__global__ __launch_bounds__(256) void neg_half_norms(const float* __restrict__ data,
                                                      float* __restrict__ nhn) {
    const int p = blockIdx.x * 256 + threadIdx.x;
    const float4* r = (const float4*)(data + (size_t)p * D);
    float4 a = r[0], b = r[1], c = r[2], e = r[3];
    float n = a.x * a.x;
    n = fmaf(a.y, a.y, n); n = fmaf(a.z, a.z, n); n = fmaf(a.w, a.w, n);
    n = fmaf(b.x, b.x, n); n = fmaf(b.y, b.y, n); n = fmaf(b.z, b.z, n); n = fmaf(b.w, b.w, n);
    n = fmaf(c.x, c.x, n); n = fmaf(c.y, c.y, n); n = fmaf(c.z, c.z, n); n = fmaf(c.w, c.w, n);
    n = fmaf(e.x, e.x, n); n = fmaf(e.y, e.y, n); n = fmaf(e.z, e.z, n); n = fmaf(e.w, e.w, n);
    nhn[p] = -0.5f * n;
}

__global__ __launch_bounds__(256) void knn_partial_fb(const float* __restrict__ x,
                                                      const float* __restrict__ data,
                                                      const float* __restrict__ nhn,
                                                      float* __restrict__ part, int cp) {
    const int q     = blockIdx.x * 256 + threadIdx.x;
    const int pbase = blockIdx.y * cp;
    const float4* xr = (const float4*)(x + (size_t)q * D);
    const float4 xa = xr[0], xb = xr[1], xc = xr[2], xd = xr[3];
    const float* dp = data + (size_t)pbase * D;
    const float* np = nhn + pbase;
    float best = -FLT_MAX;
    for (int i = 0; i < cp; i += 4) {
#pragma unroll
        for (int j = 0; j < 4; ++j) {
            const float* r  = dp + (size_t)(i + j) * D;
            const float  hn = np[i + j];
            float ca = xa.x * r[0];
            ca = fmaf(xa.y, r[1], ca);  ca = fmaf(xa.z, r[2], ca);  ca = fmaf(xa.w, r[3], ca);
            ca = fmaf(xb.x, r[4], ca);  ca = fmaf(xb.y, r[5], ca);  ca = fmaf(xb.z, r[6], ca);
            ca = fmaf(xb.w, r[7], ca);
            float cb = fmaf(xc.x, r[8], hn);
            cb = fmaf(xc.y, r[9],  cb); cb = fmaf(xc.z, r[10], cb); cb = fmaf(xc.w, r[11], cb);
            cb = fmaf(xd.x, r[12], cb); cb = fmaf(xd.y, r[13], cb); cb = fmaf(xd.z, r[14], cb);
            cb = fmaf(xd.w, r[15], cb);
            best = fmaxf(best, ca + cb);
        }
    }
    part[(size_t)blockIdx.y * NQ + q] = best;
}

__global__ __launch_bounds__(256) void knn_final_fb(const float* __restrict__ x,
                                                    const float* __restrict__ part,
                                                    float* __restrict__ out, int S) {
    const int q = blockIdx.x * 256 + threadIdx.x;
    const float4* xr = (const float4*)(x + (size_t)q * D);
    float4 a = xr[0], b = xr[1], c = xr[2], e = xr[3];
    float x2 = a.x * a.x;
    x2 = fmaf(a.y, a.y, x2); x2 = fmaf(a.z, a.z, x2); x2 = fmaf(a.w, a.w, x2);
    x2 = fmaf(b.x, b.x, x2); x2 = fmaf(b.y, b.y, x2); x2 = fmaf(b.z, b.z, x2); x2 = fmaf(b.w, b.w, x2);
    x2 = fmaf(c.x, c.x, x2); x2 = fmaf(c.y, c.y, x2); x2 = fmaf(c.z, c.z, x2); x2 = fmaf(c.w, c.w, x2);
    x2 = fmaf(e.x, e.x, x2); x2 = fmaf(e.y, e.y, x2); x2 = fmaf(e.z, e.z, x2); x2 = fmaf(e.w, e.w, x2);
    float mb = -FLT_MAX;
    for (int cI = 0; cI < S; ++cI) mb = fmaxf(mb, part[(size_t)cI * NQ + q]);
    float nn2  = fmaxf(fmaf(-2.f, mb, x2), 0.f);
    float dist = sqrtf(fmaxf(nn2, 1e-12f));
    float bump = 0.f;
    if (dist < 2.0f) {
        float denom = dist * dist - 4.0f;
        bump = expf(1.0f / denom + 0.25f);
    }
    out[q] = bump;
}

extern "C" void kernel_launch(void* const* d_in, const int* in_sizes, int n_in,
                              void* d_out, int out_size, void* d_ws, size_t ws_size,
                              hipStream_t stream) {
    const float* x    = (const float*)d_in[0];   // [2048,16] fp32
    const float* data = (const float*)d_in[1];   // [65536,16] fp32
    float* out = (float*)d_out;                  // [2048] fp32

    // ws layout (bytes):
    //   Ppk  [0, 4 MiB)          ND*32 bf16
    //   nhf  [4 MiB, +256 KiB)   ND fp32
    //   part [+256 KiB)          SCH*NQ fp32 (1 MiB)
    const size_t off_nhf  = (size_t)ND * 32 * 2;             // 4194304
    const size_t off_part = off_nhf + (size_t)ND * 4;        // 4456448
    const size_t needed   = off_part + (size_t)SCH * NQ * 4; // 5505024

    if (ws_size >= needed) {
        unsigned short* Ppk = (unsigned short*)d_ws;
        float* nhf  = (float*)((char*)d_ws + off_nhf);
        float* part = (float*)((char*)d_ws + off_part);

        pack_data<<<ND / 256, 256, 0, stream>>>(data, Ppk, nhf);
        knn_mfma<<<dim3(SCH, QCOLS), 256, 0, stream>>>(x, Ppk, nhf, part);
        knn_final<<<NQ / 256, 256, 0, stream>>>(x, part, out);
    } else {
        int S = 32;
        while (S > 1 && (size_t)(ND + S * NQ) * sizeof(float) > ws_size) S >>= 1;
        const int cp = ND / S;
        float* nhn  = (float*)d_ws;
        float* part = (float*)d_ws + ND;
        neg_half_norms<<<ND / 256, 256, 0, stream>>>(data, nhn);
        knn_partial_fb<<<dim3(NQ / 256, S), 256, 0, stream>>>(x, data, nhn, part, cp);
        knn_final_fb<<<NQ / 256, 256, 0, stream>>>(x, part, out, S);
    }
}